// Round 1
// baseline (5856.827 us; speedup 1.0000x reference)
//
#include <hip/hip_runtime.h>

#define SEQ   512
#define BATCH 64
#define D_IN  1024
#define D_LAT 1024
#define D_CAT 2048
#define NBLK  128      // j-blocks; each owns 8 output columns (j) x 4 gates = 32 W rows
#define JPB   8
#define ROWS  32
#define THREADS 512    // 8 waves: wave w owns k-chunk [256w, 256w+256) (w<4: h-part, w>=4: x-part)
#define GPS   67       // partial-gates batch stride: 67 = 3 dwords mod 32 -> <=3-way bank alias (free-ish)

typedef unsigned short u16;
typedef __attribute__((ext_vector_type(8))) short short8;   // bf16x8 MFMA frag (4 VGPRs)
typedef __attribute__((ext_vector_type(4))) float floatx4;  // fp32x4 accumulator

__device__ __forceinline__ u16 f2bf(float f) {
    union { float f; unsigned u; } a; a.f = f;
    unsigned u = a.u;
    return (u16)((u + 0x7FFFu + ((u >> 16) & 1u)) >> 16);   // RNE
}

__device__ __forceinline__ float sigm(float x)  { return 1.0f / (1.0f + __expf(-x)); }
__device__ __forceinline__ float tanhf_(float x){ return 2.0f / (1.0f + __expf(-2.0f * x)) - 1.0f; }

// Device-scope grid barrier, NO cache-maintenance fences.
// Safety argument: (1) h-stores are sc1 write-through (agent-scope relaxed
// atomics) and are vmcnt-drained by the __syncthreads before arrival, so they
// are at the coherence point before bar[0] is bumped. (2) h-loads use fresh
// addresses (hhist[t] written exactly once, read only after the barrier), so
// no cache can hold a stale copy. (3) bar[] accesses are agent-scope atomics
// (proven to observe remote-XCD stores in round 1's spin loop).
__device__ __forceinline__ void gridbar(unsigned* bar, int step) {
    __syncthreads();   // emits s_waitcnt vmcnt(0) lgkmcnt(0) + s_barrier
    if (threadIdx.x == 0) {
        unsigned prev = __hip_atomic_fetch_add(&bar[0], 1u, __ATOMIC_RELAXED,
                                               __HIP_MEMORY_SCOPE_AGENT);
        unsigned target = (unsigned)(step + 1) * NBLK;
        if (prev == target - 1u) {
            __hip_atomic_store(&bar[1], (unsigned)(step + 1), __ATOMIC_RELAXED,
                               __HIP_MEMORY_SCOPE_AGENT);
        } else {
            while (__hip_atomic_load(&bar[1], __ATOMIC_RELAXED,
                                     __HIP_MEMORY_SCOPE_AGENT) < (unsigned)(step + 1)) {
                __builtin_amdgcn_s_sleep(1);
            }
        }
    }
    __syncthreads();
    asm volatile("" ::: "memory");   // keep next step's loads below the barrier
}

__global__ void cvt_bf16(const float* __restrict__ x, u16* __restrict__ xb, int n8) {
    int i = blockIdx.x * blockDim.x + threadIdx.x;
    int stride = gridDim.x * blockDim.x;
    for (; i < n8; i += stride) {
        float4 v0 = ((const float4*)x)[2 * i];
        float4 v1 = ((const float4*)x)[2 * i + 1];
        short8 o;
        o[0] = (short)f2bf(v0.x); o[1] = (short)f2bf(v0.y);
        o[2] = (short)f2bf(v0.z); o[3] = (short)f2bf(v0.w);
        o[4] = (short)f2bf(v1.x); o[5] = (short)f2bf(v1.y);
        o[6] = (short)f2bf(v1.z); o[7] = (short)f2bf(v1.w);
        *(short8*)(xb + 8 * (size_t)i) = o;
    }
}

__launch_bounds__(THREADS, 1)
__global__ void lstm_persist(const float* __restrict__ Wf, const float* __restrict__ bfp,
                             const float* __restrict__ Wi, const float* __restrict__ bip,
                             const float* __restrict__ Wo, const float* __restrict__ bop,
                             const float* __restrict__ Wc, const float* __restrict__ bcp,
                             const u16* __restrict__ xb,     // [SEQ*BATCH*D_IN] bf16
                             u16* __restrict__ hhist,        // [(SEQ+1)*BATCH*D_LAT] bf16
                             float* __restrict__ out,        // [SEQ*BATCH*D_LAT]
                             unsigned* __restrict__ bar) {
    // LDS: ONLY the 8-way k-chunk partial sums + bias. Weights live in VGPRs.
    __shared__ __align__(16) float gp[8][ROWS][GPS];         // 68608 B
    __shared__ float biasL[ROWS];

    const int tid  = threadIdx.x;
    const int jblk = blockIdx.x;
    const int c    = tid >> 6;          // wave id == k-chunk 0..7 (0-3: h, 4-7: x)
    const int lane = tid & 63;
    const int m    = lane & 15;         // W-row-in-tile (B n-index) == C col
    const int q    = lane >> 4;         // k-quad within k-step

    // ---- one-time: this wave's B fragments -> registers (2 row-tiles x 8 k-steps) ----
    // B-frag layout for mfma_f32_16x16x32_bf16 (mirrors the proven LDS read):
    //   lane(m,q) holds W[rowtile*16+m][K0 + q*8 .. q*8+7], K0 = c*256 + ks*32.
    short8 breg[2][8];                  // 64 VGPRs, resident for all 512 steps
    #pragma unroll
    for (int rt = 0; rt < 2; ++rt) {
        const int rr  = rt * 16 + m;            // 0..31: gate g = rr>>3, j-in-block = rr&7
        const int g   = rr >> 3;
        const int jj2 = rr & 7;
        const float* Wg = (g == 0) ? Wf : (g == 1) ? Wi : (g == 2) ? Wo : Wc;
        const float* bp = Wg + (size_t)(jblk * JPB + jj2) * D_CAT + c * 256 + q * 8;
        #pragma unroll
        for (int ks = 0; ks < 8; ++ks) {
            float4 v0 = *(const float4*)(bp + ks * 32);
            float4 v1 = *(const float4*)(bp + ks * 32 + 4);
            short8 b;
            b[0] = (short)f2bf(v0.x); b[1] = (short)f2bf(v0.y);
            b[2] = (short)f2bf(v0.z); b[3] = (short)f2bf(v0.w);
            b[4] = (short)f2bf(v1.x); b[5] = (short)f2bf(v1.y);
            b[6] = (short)f2bf(v1.z); b[7] = (short)f2bf(v1.w);
            breg[rt][ks] = b;
        }
    }
    if (tid < ROWS) {
        const float* bsrc = (tid < 8) ? bfp : (tid < 16) ? bip : (tid < 24) ? bop : bcp;
        biasL[tid] = bsrc[jblk * JPB + (tid & 7)];
    }
    __syncthreads();

    // combine mapping: threads 0..255 -> (b = tid>>2, jpair a = tid&3)
    const int cb = tid >> 2;            // batch (valid for tid<256)
    const int ca = tid & 3;             // j pair -> jj = {2a, 2a+1}
    float creg0 = 0.0f, creg1 = 0.0f;   // c state, lives all 512 steps

    const int colbase = (c & 3) * 256 + q * 8;   // k offset within this chunk's source

    #pragma unroll 1
    for (int t = 0; t < SEQ; ++t) {
        // x-chunk waves (c>=4) have no dependence on the barrier's h data and
        // start their loads+MFMAs immediately, hiding the h-load latency of c<4.
        const u16* zsrc = (c < 4) ? (hhist + (size_t)t * (BATCH * D_LAT))
                                  : (xb + (size_t)t * (BATCH * D_IN));
        const u16* aptr = zsrc + colbase;

        floatx4 acc[2][4];
        #pragma unroll
        for (int rt = 0; rt < 2; ++rt)
            #pragma unroll
            for (int bt = 0; bt < 4; ++bt)
                acc[rt][bt] = (floatx4){0.f, 0.f, 0.f, 0.f};

        // 64 MFMAs per wave: 2 row-tiles x 4 batch-tiles x 8 k-steps.
        // Each A-frag (global, 16B/lane) feeds 2 MFMAs; B-frags come from regs.
        #pragma unroll
        for (int ks = 0; ks < 8; ++ks) {
            #pragma unroll
            for (int bt = 0; bt < 4; ++bt) {
                short8 a = *(const short8*)(aptr + (size_t)(bt * 16 + m) * 1024 + ks * 32);
                acc[0][bt] = __builtin_amdgcn_mfma_f32_16x16x32_bf16(a, breg[0][ks], acc[0][bt], 0, 0, 0);
                acc[1][bt] = __builtin_amdgcn_mfma_f32_16x16x32_bf16(a, breg[1][ks], acc[1][bt], 0, 0, 0);
            }
        }

        // C-layout: n(row-in-tile)=lane&15, m(batch-in-tile)=q*4+reg
        #pragma unroll
        for (int rt = 0; rt < 2; ++rt)
            #pragma unroll
            for (int bt = 0; bt < 4; ++bt)
                #pragma unroll
                for (int r = 0; r < 4; ++r)
                    gp[c][rt * 16 + m][bt * 16 + q * 4 + r] = acc[rt][bt][r];
        __syncthreads();

        // elementwise: threads 0..255, each does jj = 2a and 2a+1 for batch cb
        if (tid < 256) {
            float h0, h1;
            {
                const int jj = 2 * ca;
                float pf = biasL[jj], pi = biasL[8 + jj], po = biasL[16 + jj], pg = biasL[24 + jj];
                #pragma unroll
                for (int cc = 0; cc < 8; ++cc) {
                    pf += gp[cc][jj][cb];
                    pi += gp[cc][8 + jj][cb];
                    po += gp[cc][16 + jj][cb];
                    pg += gp[cc][24 + jj][cb];
                }
                float ft = sigm(pf), it = sigm(pi), ot = sigm(po), gt = tanhf_(pg);
                creg0 = ft * creg0 + it * gt;
                h0 = ot * tanhf_(creg0);
            }
            {
                const int jj = 2 * ca + 1;
                float pf = biasL[jj], pi = biasL[8 + jj], po = biasL[16 + jj], pg = biasL[24 + jj];
                #pragma unroll
                for (int cc = 0; cc < 8; ++cc) {
                    pf += gp[cc][jj][cb];
                    pi += gp[cc][8 + jj][cb];
                    po += gp[cc][16 + jj][cb];
                    pg += gp[cc][24 + jj][cb];
                }
                float ft = sigm(pf), it = sigm(pi), ot = sigm(po), gt = tanhf_(pg);
                creg1 = ft * creg1 + it * gt;
                h1 = ot * tanhf_(creg1);
            }
            const int jglob = jblk * JPB + 2 * ca;
            // packed sc1 write-through h store (2 x bf16 in one u32)
            unsigned hv = (unsigned)f2bf(h0) | ((unsigned)f2bf(h1) << 16);
            unsigned* hp = (unsigned*)(hhist + (size_t)(t + 1) * (BATCH * D_LAT)
                                             + (size_t)cb * D_LAT + jglob);
            __hip_atomic_store(hp, hv, __ATOMIC_RELAXED, __HIP_MEMORY_SCOPE_AGENT);
            // fp32 out store (8B)
            float2 ov = make_float2(h0, h1);
            *(float2*)(out + (size_t)t * (BATCH * D_LAT) + (size_t)cb * D_LAT + jglob) = ov;
        }

        gridbar(bar, t);
    }
}

extern "C" void kernel_launch(void* const* d_in, const int* in_sizes, int n_in,
                              void* d_out, int out_size, void* d_ws, size_t ws_size,
                              hipStream_t stream) {
    const float* x  = (const float*)d_in[0];
    const float* Wf = (const float*)d_in[1];
    const float* bf = (const float*)d_in[2];
    const float* Wi = (const float*)d_in[3];
    const float* bi = (const float*)d_in[4];
    const float* Wo = (const float*)d_in[5];
    const float* bo = (const float*)d_in[6];
    const float* Wc = (const float*)d_in[7];
    const float* bc = (const float*)d_in[8];
    float* out = (float*)d_out;

    char* ws = (char*)d_ws;
    unsigned* bar = (unsigned*)ws;
    u16* hhist = (u16*)(ws + 1024);                                      // 513*64*1024*2 B
    u16* xb    = (u16*)(ws + 1024 + (size_t)(SEQ + 1) * BATCH * D_LAT * 2);

    // zero barrier vars + h_hist[0] (contiguous region)
    hipMemsetAsync(ws, 0, 1024 + (size_t)BATCH * D_LAT * 2, stream);
    cvt_bf16<<<2048, 256, 0, stream>>>(x, xb, SEQ * BATCH * D_IN / 8);
    lstm_persist<<<NBLK, THREADS, 0, stream>>>(Wf, bf, Wi, bi, Wo, bo, Wc, bc,
                                               xb, hhist, out, bar);
}

// Round 2
// 4897.854 us; speedup vs baseline: 1.1958x; 1.1958x over previous
//
#include <hip/hip_runtime.h>

#define SEQ   512
#define BATCH 64
#define D_IN  1024
#define D_LAT 1024
#define D_CAT 2048
#define NBLK  128      // j-blocks; each owns 8 output columns (j) x 4 gates = 32 W rows
#define JPB   8
#define ROWS  32
#define THREADS 512    // 8 waves: wave c owns h-cols [128c,128c+128) AND x-cols [128c,128c+128)
#define GPS   67       // partial-gates batch stride: 67 = 3 dwords mod 32 -> <=3-way bank alias

typedef unsigned short u16;
typedef __attribute__((ext_vector_type(8))) short short8;   // bf16x8 MFMA frag (4 VGPRs)
typedef __attribute__((ext_vector_type(4))) float floatx4;  // fp32x4 accumulator

__device__ __forceinline__ u16 f2bf(float f) {
    union { float f; unsigned u; } a; a.f = f;
    unsigned u = a.u;
    return (u16)((u + 0x7FFFu + ((u >> 16) & 1u)) >> 16);   // RNE
}

__device__ __forceinline__ float sigm(float x)  { return 1.0f / (1.0f + __expf(-x)); }
__device__ __forceinline__ float tanhf_(float x){ return 2.0f / (1.0f + __expf(-2.0f * x)) - 1.0f; }

__global__ void cvt_bf16(const float* __restrict__ x, u16* __restrict__ xb, int n8) {
    int i = blockIdx.x * blockDim.x + threadIdx.x;
    int stride = gridDim.x * blockDim.x;
    for (; i < n8; i += stride) {
        float4 v0 = ((const float4*)x)[2 * i];
        float4 v1 = ((const float4*)x)[2 * i + 1];
        short8 o;
        o[0] = (short)f2bf(v0.x); o[1] = (short)f2bf(v0.y);
        o[2] = (short)f2bf(v0.z); o[3] = (short)f2bf(v0.w);
        o[4] = (short)f2bf(v1.x); o[5] = (short)f2bf(v1.y);
        o[6] = (short)f2bf(v1.z); o[7] = (short)f2bf(v1.w);
        *(short8*)(xb + 8 * (size_t)i) = o;
    }
}

// Barrier memory layout in ws (zeroed): bar[0]=global arrive count (line 0),
// bar[16]=release step (line 1), bar[32+16*g]=per-group arrive counts (lines 2..9).
// All counters monotonic across steps -> no reset race.

__launch_bounds__(THREADS, 1)
__global__ void lstm_persist(const float* __restrict__ Wf, const float* __restrict__ bfp,
                             const float* __restrict__ Wi, const float* __restrict__ bip,
                             const float* __restrict__ Wo, const float* __restrict__ bop,
                             const float* __restrict__ Wc, const float* __restrict__ bcp,
                             const u16* __restrict__ xb,     // [SEQ*BATCH*D_IN] bf16
                             u16* __restrict__ hhist,        // [(SEQ+1)*BATCH*D_LAT] bf16
                             float* __restrict__ out,        // [SEQ*BATCH*D_LAT]
                             unsigned* __restrict__ bar) {
    // LDS: ONLY the 8-way k-chunk partial sums + bias. Weights live in VGPRs.
    __shared__ __align__(16) float gp[8][ROWS][GPS];         // 68608 B
    __shared__ float biasL[ROWS];

    const int tid  = threadIdx.x;
    const int jblk = blockIdx.x;
    const int c    = tid >> 6;          // wave id == 128-wide k-chunk 0..7
    const int lane = tid & 63;
    const int m    = lane & 15;         // W-row-in-tile (B n-index) == C col
    const int q    = lane >> 4;         // k-quad within k-step
    const int grp  = jblk & 7;          // arrive group (~XCD)

    // ---- one-time: this wave's B fragments -> registers ----
    // Wave c holds W cols [c*128, c*128+128) of the h-part AND of the x-part,
    // for both 16-row tiles: 2 tiles x 4 k-steps x 2 parts = 64 VGPRs resident.
    short8 bregH[2][4], bregX[2][4];
    #pragma unroll
    for (int rt = 0; rt < 2; ++rt) {
        const int rr  = rt * 16 + m;            // 0..31: gate g = rr>>3, j-in-block = rr&7
        const int g   = rr >> 3;
        const int jj2 = rr & 7;
        const float* Wg = (g == 0) ? Wf : (g == 1) ? Wi : (g == 2) ? Wo : Wc;
        const float* rowp = Wg + (size_t)(jblk * JPB + jj2) * D_CAT;
        #pragma unroll
        for (int ks = 0; ks < 4; ++ks) {
            const float* ph = rowp + c * 128 + ks * 32 + q * 8;          // h cols
            const float* px = rowp + 1024 + c * 128 + ks * 32 + q * 8;   // x cols
            float4 h0 = *(const float4*)(ph);
            float4 h1 = *(const float4*)(ph + 4);
            float4 x0 = *(const float4*)(px);
            float4 x1 = *(const float4*)(px + 4);
            short8 bh, bx;
            bh[0] = (short)f2bf(h0.x); bh[1] = (short)f2bf(h0.y);
            bh[2] = (short)f2bf(h0.z); bh[3] = (short)f2bf(h0.w);
            bh[4] = (short)f2bf(h1.x); bh[5] = (short)f2bf(h1.y);
            bh[6] = (short)f2bf(h1.z); bh[7] = (short)f2bf(h1.w);
            bx[0] = (short)f2bf(x0.x); bx[1] = (short)f2bf(x0.y);
            bx[2] = (short)f2bf(x0.z); bx[3] = (short)f2bf(x0.w);
            bx[4] = (short)f2bf(x1.x); bx[5] = (short)f2bf(x1.y);
            bx[6] = (short)f2bf(x1.z); bx[7] = (short)f2bf(x1.w);
            bregH[rt][ks] = bh;
            bregX[rt][ks] = bx;
        }
    }
    if (tid < ROWS) {
        const float* bsrc = (tid < 8) ? bfp : (tid < 16) ? bip : (tid < 24) ? bop : bcp;
        biasL[tid] = bsrc[jblk * JPB + (tid & 7)];
    }
    __syncthreads();

    // combine mapping: threads 0..255 -> (b = tid>>2, jpair a = tid&3)
    const int cb = tid >> 2;            // batch (valid for tid<256)
    const int ca = tid & 3;             // j pair -> jj = {2a, 2a+1}
    float creg0 = 0.0f, creg1 = 0.0f;   // c state, lives all 512 steps

    const int colbase = c * 128 + q * 8;   // k offset within h (or x) for this wave

    #pragma unroll 1
    for (int t = 0; t < SEQ; ++t) {
        // ================= PHASE 1: x-half (no barrier dependency) =================
        // Runs while the previous step's release is still propagating across XCDs.
        const u16* xptr = xb + (size_t)t * (BATCH * D_IN) + colbase;

        floatx4 acc[2][4];
        #pragma unroll
        for (int rt = 0; rt < 2; ++rt)
            #pragma unroll
            for (int bt = 0; bt < 4; ++bt)
                acc[rt][bt] = (floatx4){0.f, 0.f, 0.f, 0.f};

        #pragma unroll
        for (int ks = 0; ks < 4; ++ks) {
            #pragma unroll
            for (int bt = 0; bt < 4; ++bt) {
                short8 a = *(const short8*)(xptr + (size_t)(bt * 16 + m) * 1024 + ks * 32);
                acc[0][bt] = __builtin_amdgcn_mfma_f32_16x16x32_bf16(a, bregX[0][ks], acc[0][bt], 0, 0, 0);
                acc[1][bt] = __builtin_amdgcn_mfma_f32_16x16x32_bf16(a, bregX[1][ks], acc[1][bt], 0, 0, 0);
            }
        }

        // ================= PHASE 2: wait for h[t] release ==========================
        asm volatile("" ::: "memory");
        if (tid == 0) {
            while (__hip_atomic_load(&bar[16], __ATOMIC_RELAXED,
                                     __HIP_MEMORY_SCOPE_AGENT) < (unsigned)t) {
                __builtin_amdgcn_s_sleep(2);
            }
        }
        __syncthreads();
        asm volatile("" ::: "memory");   // keep h-loads below the release observation

        // ================= PHASE 3: h-half (critical path) =========================
        const u16* hptr = hhist + (size_t)t * (BATCH * D_LAT) + colbase;
        #pragma unroll
        for (int ks = 0; ks < 4; ++ks) {
            #pragma unroll
            for (int bt = 0; bt < 4; ++bt) {
                short8 a = *(const short8*)(hptr + (size_t)(bt * 16 + m) * 1024 + ks * 32);
                acc[0][bt] = __builtin_amdgcn_mfma_f32_16x16x32_bf16(a, bregH[0][ks], acc[0][bt], 0, 0, 0);
                acc[1][bt] = __builtin_amdgcn_mfma_f32_16x16x32_bf16(a, bregH[1][ks], acc[1][bt], 0, 0, 0);
            }
        }

        // C-layout: n(row-in-tile)=lane&15, m(batch-in-tile)=q*4+reg
        #pragma unroll
        for (int rt = 0; rt < 2; ++rt)
            #pragma unroll
            for (int bt = 0; bt < 4; ++bt)
                #pragma unroll
                for (int r = 0; r < 4; ++r)
                    gp[c][rt * 16 + m][bt * 16 + q * 4 + r] = acc[rt][bt][r];
        __syncthreads();

        // ================= PHASE 4: elementwise + h store ==========================
        if (tid < 256) {
            float h0, h1;
            {
                const int jj = 2 * ca;
                float pf = biasL[jj], pi = biasL[8 + jj], po = biasL[16 + jj], pg = biasL[24 + jj];
                #pragma unroll
                for (int cc = 0; cc < 8; ++cc) {
                    pf += gp[cc][jj][cb];
                    pi += gp[cc][8 + jj][cb];
                    po += gp[cc][16 + jj][cb];
                    pg += gp[cc][24 + jj][cb];
                }
                float ft = sigm(pf), it = sigm(pi), ot = sigm(po), gt = tanhf_(pg);
                creg0 = ft * creg0 + it * gt;
                h0 = ot * tanhf_(creg0);
            }
            {
                const int jj = 2 * ca + 1;
                float pf = biasL[jj], pi = biasL[8 + jj], po = biasL[16 + jj], pg = biasL[24 + jj];
                #pragma unroll
                for (int cc = 0; cc < 8; ++cc) {
                    pf += gp[cc][jj][cb];
                    pi += gp[cc][8 + jj][cb];
                    po += gp[cc][16 + jj][cb];
                    pg += gp[cc][24 + jj][cb];
                }
                float ft = sigm(pf), it = sigm(pi), ot = sigm(po), gt = tanhf_(pg);
                creg1 = ft * creg1 + it * gt;
                h1 = ot * tanhf_(creg1);
            }
            const int jglob = jblk * JPB + 2 * ca;
            // packed sc1 write-through h store (2 x bf16 in one u32)
            unsigned hv = (unsigned)f2bf(h0) | ((unsigned)f2bf(h1) << 16);
            unsigned* hp = (unsigned*)(hhist + (size_t)(t + 1) * (BATCH * D_LAT)
                                             + (size_t)cb * D_LAT + jglob);
            __hip_atomic_store(hp, hv, __ATOMIC_RELAXED, __HIP_MEMORY_SCOPE_AGENT);
            // fp32 out store (8B)
            float2 ov = make_float2(h0, h1);
            *(float2*)(out + (size_t)t * (BATCH * D_LAT) + (size_t)cb * D_LAT + jglob) = ov;
        }

        // syncthreads drains every thread's vmcnt -> all h-stores are at the
        // coherence point before this block's arrive below.
        __syncthreads();

        // ================= PHASE 5: hierarchical arrive (fire-and-forget) ==========
        if (tid == 0) {
            unsigned pg = __hip_atomic_fetch_add(&bar[32 + 16 * grp], 1u, __ATOMIC_RELAXED,
                                                 __HIP_MEMORY_SCOPE_AGENT);
            if (pg == (unsigned)(t + 1) * (NBLK / 8) - 1u) {       // last in group
                unsigned pa = __hip_atomic_fetch_add(&bar[0], 1u, __ATOMIC_RELAXED,
                                                     __HIP_MEMORY_SCOPE_AGENT);
                if (pa == (unsigned)(t + 1) * 8u - 1u) {           // last group
                    __hip_atomic_store(&bar[16], (unsigned)(t + 1), __ATOMIC_RELAXED,
                                       __HIP_MEMORY_SCOPE_AGENT);
                }
            }
        }
        asm volatile("" ::: "memory");
    }
}

extern "C" void kernel_launch(void* const* d_in, const int* in_sizes, int n_in,
                              void* d_out, int out_size, void* d_ws, size_t ws_size,
                              hipStream_t stream) {
    const float* x  = (const float*)d_in[0];
    const float* Wf = (const float*)d_in[1];
    const float* bf = (const float*)d_in[2];
    const float* Wi = (const float*)d_in[3];
    const float* bi = (const float*)d_in[4];
    const float* Wo = (const float*)d_in[5];
    const float* bo = (const float*)d_in[6];
    const float* Wc = (const float*)d_in[7];
    const float* bc = (const float*)d_in[8];
    float* out = (float*)d_out;

    char* ws = (char*)d_ws;
    unsigned* bar = (unsigned*)ws;
    u16* hhist = (u16*)(ws + 1024);                                      // 513*64*1024*2 B
    u16* xb    = (u16*)(ws + 1024 + (size_t)(SEQ + 1) * BATCH * D_LAT * 2);

    // zero barrier vars + h_hist[0] (contiguous region)
    hipMemsetAsync(ws, 0, 1024 + (size_t)BATCH * D_LAT * 2, stream);
    cvt_bf16<<<2048, 256, 0, stream>>>(x, xb, SEQ * BATCH * D_IN / 8);
    lstm_persist<<<NBLK, THREADS, 0, stream>>>(Wf, bf, Wi, bi, Wo, bo, Wc, bc,
                                               xb, hhist, out, bar);
}